// Round 18
// baseline (90.043 us; speedup 1.0000x reference)
//
#include <hip/hip_runtime.h>
#include <hip/hip_bf16.h>
#include <stdint.h>

#define E_EXP 16
#define H_DIM 1024
#define BK 64
#define WBM 32         // per-wave (=per-block) output rows (halved vs R14)
#define WBN 64         // per-wave output cols
#define NSLOT 16       // one slot per nb
#define B_TOK 4096
#define KS 16          // router k-splits
#define KC 64          // H_DIM / KS
#define RTM 128        // router token tile
#define RSTRIDE (KC + 4)

typedef short bf16x8 __attribute__((ext_vector_type(8)));
typedef float f32x4 __attribute__((ext_vector_type(4)));

__device__ __forceinline__ unsigned short f2bf(float x) {
  union { float f; unsigned u; } v; v.f = x;
  unsigned r = v.u + 0x7FFFu + ((v.u >> 16) & 1u);   // RNE
  return (unsigned short)(r >> 16);
}

__device__ __forceinline__ void gload_lds16(const void* g, void* l) {
  __builtin_amdgcn_global_load_lds(
      (const __attribute__((address_space(1))) void*)g,
      (__attribute__((address_space(3))) void*)l, 16, 0, 0);
}

// ---------------- Prep: router partial-logit GEMM  ∪  W1 transpose ---------
// Also zeroes counts (block 0) — saves the memset dispatch.
__global__ __launch_bounds__(256) void k_prep(
    const float* __restrict__ emb, const float* __restrict__ rw,
    const float* __restrict__ w1, unsigned short* __restrict__ emb_bf,
    float* __restrict__ part, unsigned short* __restrict__ w1t,
    int* __restrict__ counts)
{
  __shared__ __align__(16) char smem[RTM * RSTRIDE * 4 + KC * E_EXP * 4];
  const int tid = threadIdx.x;

  if (blockIdx.x == 0 && tid < E_EXP) counts[tid] = 0;

  if (blockIdx.x < 512) {
    // ---- router GEMM: partial logits [KS][B][16] + emb->bf16 ----
    float* embL = (float*)smem;                       // 128 x 68
    float* rwL  = (float*)(smem + RTM * RSTRIDE * 4); // 64 x 16
    const int t0 = (blockIdx.x & 31) * RTM;
    const int ks = blockIdx.x >> 5;

#pragma unroll
    for (int it = 0; it < 8; ++it) {
      const int i = tid + 256 * it;       // 0..2047 = 128 rows x 16 f32x4
      const int row = i >> 4;
      const int c4 = i & 15;
      const size_t goff = (size_t)(t0 + row) * H_DIM + ks * KC + c4 * 4;
      const f32x4 v = *(const f32x4*)(emb + goff);
      ushort4 o;
      o.x = f2bf(v[0]); o.y = f2bf(v[1]); o.z = f2bf(v[2]); o.w = f2bf(v[3]);
      *(ushort4*)(emb_bf + goff) = o;
      *(f32x4*)(embL + row * RSTRIDE + c4 * 4) = v;
    }
    {
      const f32x4 v = *(const f32x4*)(rw + (size_t)ks * (KC * E_EXP) + tid * 4);
      *(f32x4*)(rwL + tid * 4) = v;
    }
    __syncthreads();

    const int w = tid >> 6, lane = tid & 63;
    const int tg = lane & 15, eg = lane >> 4;
    const int ta = w * 32 + tg, tb = ta + 16;

    f32x4 accA = {0.f, 0.f, 0.f, 0.f};
    f32x4 accB = {0.f, 0.f, 0.f, 0.f};
#pragma unroll
    for (int k4 = 0; k4 < KC / 4; ++k4) {
      const f32x4 e0 = *(const f32x4*)(embL + ta * RSTRIDE + k4 * 4);
      const f32x4 e1 = *(const f32x4*)(embL + tb * RSTRIDE + k4 * 4);
#pragma unroll
      for (int h = 0; h < 4; ++h) {
        const f32x4 r = *(const f32x4*)(rwL + (k4 * 4 + h) * E_EXP + eg * 4);
        accA += e0[h] * r;
        accB += e1[h] * r;
      }
    }
    *(f32x4*)(part + ((size_t)ks * B_TOK + t0 + ta) * E_EXP + eg * 4) = accA;
    *(f32x4*)(part + ((size_t)ks * B_TOK + t0 + tb) * E_EXP + eg * 4) = accB;
  } else {
    // ---- W1 [e][h][d] fp32 -> W1T [e][d][h] bf16 ----
    typedef unsigned short TileT[65];
    TileT* tile = (TileT*)smem;                       // 64 x 65 shorts
    const int wb = blockIdx.x - 512;
    const int e  = wb >> 8;
    const int ht = (wb >> 4) & 15;
    const int dt = wb & 15;
    const float* src = w1 + ((size_t)e * H_DIM + ht * 64) * H_DIM + dt * 64;
    const int tr = tid >> 4;
    const int tc = tid & 15;
#pragma unroll
    for (int i = 0; i < 4; ++i) {
      const int r = tr + i * 16;
      const float4 v = *(const float4*)(src + (size_t)r * H_DIM + tc * 4);
      tile[r][tc * 4 + 0] = f2bf(v.x);
      tile[r][tc * 4 + 1] = f2bf(v.y);
      tile[r][tc * 4 + 2] = f2bf(v.z);
      tile[r][tc * 4 + 3] = f2bf(v.w);
    }
    __syncthreads();
    unsigned short* dst = w1t + ((size_t)e * H_DIM + dt * 64) * H_DIM + ht * 64;
    const int wr = tid >> 3;
    const int wc = tid & 7;
#pragma unroll
    for (int i = 0; i < 2; ++i) {
      const int r = wr + i * 32;
      ushort4 t0, t1;
      t0.x = tile[wc * 8 + 0][r]; t0.y = tile[wc * 8 + 1][r];
      t0.z = tile[wc * 8 + 2][r]; t0.w = tile[wc * 8 + 3][r];
      t1.x = tile[wc * 8 + 4][r]; t1.y = tile[wc * 8 + 5][r];
      t1.z = tile[wc * 8 + 6][r]; t1.w = tile[wc * 8 + 7][r];
      *(ushort4*)(dst + (size_t)r * H_DIM + wc * 8) = t0;
      *(ushort4*)(dst + (size_t)r * H_DIM + wc * 8 + 4) = t1;
    }
  }
}

// ---------------- Router select: reduce partials, top-2, compaction --------
__global__ __launch_bounds__(256) void k_router_select(
    const float* __restrict__ part, const float* __restrict__ rb,
    int* __restrict__ counts, int* __restrict__ lists,
    int4* __restrict__ meta, float2* __restrict__ wts)
{
  __shared__ int lcnt[E_EXP];
  __shared__ int base[E_EXP];
  const int tid = threadIdx.x;
  const int t = blockIdx.x * 256 + tid;
  if (tid < E_EXP) lcnt[tid] = 0;

  float lg[16];
#pragma unroll
  for (int q = 0; q < 4; ++q) {
    const f32x4 b = *(const f32x4*)(rb + q * 4);
    lg[q * 4 + 0] = b[0]; lg[q * 4 + 1] = b[1];
    lg[q * 4 + 2] = b[2]; lg[q * 4 + 3] = b[3];
  }
#pragma unroll
  for (int s = 0; s < KS; ++s) {
#pragma unroll
    for (int q = 0; q < 4; ++q) {
      const f32x4 v = *(const f32x4*)(part + ((size_t)s * B_TOK + t) * E_EXP + q * 4);
      lg[q * 4 + 0] += v[0]; lg[q * 4 + 1] += v[1];
      lg[q * 4 + 2] += v[2]; lg[q * 4 + 3] += v[3];
    }
  }

  float best = -1e30f; int b0 = 0;
#pragma unroll
  for (int e = 0; e < 16; ++e)
    if (lg[e] > best) { best = lg[e]; b0 = e; }
  float best2 = -1e30f; int b1i = 0;
#pragma unroll
  for (int e = 0; e < 16; ++e)
    if (e != b0 && lg[e] > best2) { best2 = lg[e]; b1i = e; }

  __syncthreads();                       // lcnt zeroed
  const int l0 = atomicAdd(&lcnt[b0], 1);
  const int l1 = atomicAdd(&lcnt[b1i], 1);
  __syncthreads();
  if (tid < E_EXP) base[tid] = atomicAdd(&counts[tid], lcnt[tid]);
  __syncthreads();

  const int p0 = base[b0] + l0;
  const int p1 = base[b1i] + l1;
  lists[b0 * B_TOK + p0] = t;
  lists[b1i * B_TOK + p1] = t;
  meta[t] = make_int4(b0, b1i, p0, p1);
  const float e1v = expf(best2 - best);
  const float w0 = 1.f / (1.f + e1v);
  wts[t] = make_float2(w0, e1v * w0);
}

// ---------------- Grouped GEMM: barrier-free 1-wave blocks, 32x64 tiles ----
// R14 structure verbatim (per-wave s_waitcnt only, simple vmcnt(0) loop —
// every dbuf/counted-vmcnt variant R15/R16/R17 regressed) with tile M
// halved 64->32: real blocks double to 4096 -> 4 waves/SIMD co-resident
// (was 2). Residency was work-limited, not resource-limited; wave-TLP is
// the one lever that has ever paid in this regime.
__global__ __launch_bounds__(64) void k_moe_gemm(
    const unsigned short* __restrict__ emb_bf,
    const unsigned short* __restrict__ w1t,
    const float* __restrict__ b1, const float* __restrict__ w2,
    const int* __restrict__ counts, const int* __restrict__ lists,
    float* __restrict__ outbuf)
{
  const int bid = blockIdx.x;        // 4096
  const int xcd = bid & 7;
  const int j = bid >> 3;            // 0..511
  const int e  = xcd + 8 * (j >> 8); // experts {xcd, xcd+8} on this XCD
  const int r  = j & 255;
  const int nb = r >> 4;             // 0..15 (N tile of 64)
  const int mbg = r & 15;            // mb base (32-row tiles), stride 16
  const int cnt = counts[e];

  __shared__ unsigned short lA[WBM * BK];   // 4 KB, 128B rows, XOR-swizzled
  __shared__ unsigned short lB[WBN * BK];   // 8 KB, same layout

  const int lane = threadIdx.x;
  // swizzled source column byte: dest byte-in-row = (lane&7)*16, row&7 = lane>>3
  const int scb = ((lane & 7) * 16) ^ ((lane >> 3) << 4);
  const int lr = lane & 15, lg = lane >> 4;

  const unsigned short* w1tb = w1t + ((size_t)e * H_DIM + nb * WBN) * H_DIM;
  const float* b1e = b1 + (size_t)e * H_DIM + nb * WBN;
  const float* w2e = w2 + (size_t)e * H_DIM + nb * WBN;

  // B source rows (8 chunks of 1 KB), fixed across mb iterations
  const unsigned short* bSrc[8];
#pragma unroll
  for (int i = 0; i < 8; ++i) {
    const int n = i * 8 + (lane >> 3);
    bSrc[i] = w1tb + (size_t)n * H_DIM + (scb >> 1);
  }

  for (int mb = mbg; mb * WBM < cnt; mb += 16) {
    const int base = mb * WBM;

    // A source rows (4 chunks of 1 KB): token of row i*8 + (lane>>3)
    const unsigned short* aSrc[4];
#pragma unroll
    for (int i = 0; i < 4; ++i) {
      const int p = base + i * 8 + (lane >> 3);
      const int tok = lists[e * B_TOK + (p < cnt ? p : 0)];
      aSrc[i] = emb_bf + (size_t)tok * H_DIM + (scb >> 1);
    }

    f32x4 acc[2][4];
#pragma unroll
    for (int m = 0; m < 2; ++m)
#pragma unroll
      for (int n = 0; n < 4; ++n) acc[m][n] = (f32x4){0.f, 0.f, 0.f, 0.f};

#pragma unroll 1
    for (int k0 = 0; k0 < H_DIM; k0 += BK) {
      // WAR guard: previous step's ds_reads complete before restage
      asm volatile("s_waitcnt lgkmcnt(0)" ::: "memory");
      __builtin_amdgcn_sched_barrier(0);
#pragma unroll
      for (int i = 0; i < 4; ++i)
        gload_lds16(aSrc[i] + k0, (char*)lA + i * 1024);
#pragma unroll
      for (int i = 0; i < 8; ++i)
        gload_lds16(bSrc[i] + k0, (char*)lB + i * 1024);
      // per-wave: our 12 loads landed -> LDS visible to this wave
      asm volatile("s_waitcnt vmcnt(0)" ::: "memory");
      __builtin_amdgcn_sched_barrier(0);

#pragma unroll
      for (int kk = 0; kk < 2; ++kk) {
        const int kb = kk * 64 + lg * 16;
        bf16x8 af[2], bfr[4];
#pragma unroll
        for (int m = 0; m < 2; ++m) {
          const int row = m * 16 + lr;
          af[m] = *(const bf16x8*)((const char*)lA + row * 128 + (kb ^ ((row & 7) << 4)));
        }
#pragma unroll
        for (int n = 0; n < 4; ++n) {
          const int row = n * 16 + lr;
          bfr[n] = *(const bf16x8*)((const char*)lB + row * 128 + (kb ^ ((row & 7) << 4)));
        }
        __builtin_amdgcn_s_setprio(1);
#pragma unroll
        for (int m = 0; m < 2; ++m)
#pragma unroll
          for (int n = 0; n < 4; ++n)
            acc[m][n] = __builtin_amdgcn_mfma_f32_16x16x32_bf16(af[m], bfr[n], acc[m][n], 0, 0, 0);
        __builtin_amdgcn_s_setprio(0);
      }
    }

    // epilogue: relu(acc + b1) * w2, reduce over this wave's 64 cols
    float rs[2][4];
#pragma unroll
    for (int m = 0; m < 2; ++m)
#pragma unroll
      for (int r4 = 0; r4 < 4; ++r4) rs[m][r4] = 0.f;

#pragma unroll
    for (int n = 0; n < 4; ++n) {
      const int d = n * 16 + lr;
      const float bb = b1e[d];
      const float ww = w2e[d];
#pragma unroll
      for (int m = 0; m < 2; ++m)
#pragma unroll
        for (int r4 = 0; r4 < 4; ++r4) {
          float v = acc[m][n][r4] + bb;
          v = fmaxf(v, 0.f);
          rs[m][r4] = fmaf(v, ww, rs[m][r4]);
        }
    }
#pragma unroll
    for (int mask = 8; mask >= 1; mask >>= 1) {
#pragma unroll
      for (int m = 0; m < 2; ++m)
#pragma unroll
        for (int r4 = 0; r4 < 4; ++r4) rs[m][r4] += __shfl_xor(rs[m][r4], mask, 64);
    }

    if (lr == 0) {
      float* ob = outbuf + ((size_t)nb * E_EXP + e) * B_TOK + base;
#pragma unroll
      for (int m = 0; m < 2; ++m)
#pragma unroll
        for (int r4 = 0; r4 < 4; ++r4)
          ob[m * 16 + lg * 4 + r4] = rs[m][r4];
    }
  }
}

// ---------------- Combine: gather 2 experts x 16 partial slots -------------
__global__ __launch_bounds__(256) void k_combine(
    const int4* __restrict__ meta, const float2* __restrict__ wts,
    const float* __restrict__ outbuf, const float* __restrict__ b2,
    float* __restrict__ out)
{
  const int t = blockIdx.x * 256 + threadIdx.x;
  if (t >= B_TOK) return;
  const int4 m = meta[t];
  const float2 w = wts[t];
  float o0 = b2[m.x], o1 = b2[m.y];
#pragma unroll
  for (int s = 0; s < NSLOT; ++s) {
    o0 += outbuf[((size_t)s * E_EXP + m.x) * B_TOK + m.z];
    o1 += outbuf[((size_t)s * E_EXP + m.y) * B_TOK + m.w];
  }
  out[t] = w.x * o0 + w.y * o1;
}

extern "C" void kernel_launch(void* const* d_in, const int* in_sizes, int n_in,
                              void* d_out, int out_size, void* d_ws, size_t ws_size,
                              hipStream_t stream)
{
  const float* emb = (const float*)d_in[0];
  const float* rw  = (const float*)d_in[1];
  const float* rb  = (const float*)d_in[2];
  const float* w1  = (const float*)d_in[3];
  const float* b1  = (const float*)d_in[4];
  const float* w2  = (const float*)d_in[5];
  const float* b2  = (const float*)d_in[6];
  float* out = (float*)d_out;

  char* ws = (char*)d_ws;
  size_t cur = 0;
  auto alloc = [&](size_t bytes) -> void* {
    void* p = ws + cur;
    cur += (bytes + 255) & ~(size_t)255;
    return p;
  };
  int*            counts = (int*)alloc(64);
  int4*           meta   = (int4*)alloc((size_t)B_TOK * 16);
  float2*         wts    = (float2*)alloc((size_t)B_TOK * 8);
  int*            lists  = (int*)alloc((size_t)E_EXP * B_TOK * 4);
  float*          outbuf = (float*)alloc((size_t)NSLOT * E_EXP * B_TOK * 4);
  float*          part   = (float*)alloc((size_t)KS * B_TOK * E_EXP * 4);
  unsigned short* emb_bf = (unsigned short*)alloc((size_t)B_TOK * H_DIM * 2);
  unsigned short* w1t    = (unsigned short*)alloc((size_t)E_EXP * H_DIM * H_DIM * 2);

  k_prep<<<dim3(512 + 4096), 256, 0, stream>>>(emb, rw, w1, emb_bf, part, w1t, counts);
  k_router_select<<<B_TOK / 256, 256, 0, stream>>>(part, rb, counts, lists, meta, wts);
  k_moe_gemm<<<dim3(4096), 64, 0, stream>>>(emb_bf, w1t, b1, w2, counts, lists, outbuf);
  k_combine<<<B_TOK / 256, 256, 0, stream>>>(meta, wts, outbuf, b2, out);
}

// Round 19
// 75.893 us; speedup vs baseline: 1.1864x; 1.1864x over previous
//
#include <hip/hip_runtime.h>
#include <hip/hip_bf16.h>
#include <stdint.h>

#define E_EXP 16
#define H_DIM 1024
#define BK 64
#define WBM 64         // per-wave (=per-block) output rows
#define WBN 64         // per-wave output cols
#define NSLOT 16       // one slot per nb
#define B_TOK 4096
#define MBS 10         // mb grid-stride (≈8 tiles/expert; stride-loop covers skew)
#define KS 16          // router k-splits
#define KC 64          // H_DIM / KS
#define RTM 128        // router token tile
#define RSTRIDE (KC + 4)

typedef short bf16x8 __attribute__((ext_vector_type(8)));
typedef float f32x4 __attribute__((ext_vector_type(4)));

__device__ __forceinline__ unsigned short f2bf(float x) {
  union { float f; unsigned u; } v; v.f = x;
  unsigned r = v.u + 0x7FFFu + ((v.u >> 16) & 1u);   // RNE
  return (unsigned short)(r >> 16);
}

__device__ __forceinline__ void gload_lds16(const void* g, void* l) {
  __builtin_amdgcn_global_load_lds(
      (const __attribute__((address_space(1))) void*)g,
      (__attribute__((address_space(3))) void*)l, 16, 0, 0);
}

// ---------------- Prep: router partial-logit GEMM  ∪  W1 transpose ---------
// Also zeroes counts (block 0) — saves the memset dispatch.
__global__ __launch_bounds__(256) void k_prep(
    const float* __restrict__ emb, const float* __restrict__ rw,
    const float* __restrict__ w1, unsigned short* __restrict__ emb_bf,
    float* __restrict__ part, unsigned short* __restrict__ w1t,
    int* __restrict__ counts)
{
  __shared__ __align__(16) char smem[RTM * RSTRIDE * 4 + KC * E_EXP * 4];
  const int tid = threadIdx.x;

  if (blockIdx.x == 0 && tid < E_EXP) counts[tid] = 0;

  if (blockIdx.x < 512) {
    // ---- router GEMM: partial logits [KS][B][16] + emb->bf16 ----
    float* embL = (float*)smem;                       // 128 x 68
    float* rwL  = (float*)(smem + RTM * RSTRIDE * 4); // 64 x 16
    const int t0 = (blockIdx.x & 31) * RTM;
    const int ks = blockIdx.x >> 5;

#pragma unroll
    for (int it = 0; it < 8; ++it) {
      const int i = tid + 256 * it;       // 0..2047 = 128 rows x 16 f32x4
      const int row = i >> 4;
      const int c4 = i & 15;
      const size_t goff = (size_t)(t0 + row) * H_DIM + ks * KC + c4 * 4;
      const f32x4 v = *(const f32x4*)(emb + goff);
      ushort4 o;
      o.x = f2bf(v[0]); o.y = f2bf(v[1]); o.z = f2bf(v[2]); o.w = f2bf(v[3]);
      *(ushort4*)(emb_bf + goff) = o;
      *(f32x4*)(embL + row * RSTRIDE + c4 * 4) = v;
    }
    {
      const f32x4 v = *(const f32x4*)(rw + (size_t)ks * (KC * E_EXP) + tid * 4);
      *(f32x4*)(rwL + tid * 4) = v;
    }
    __syncthreads();

    const int w = tid >> 6, lane = tid & 63;
    const int tg = lane & 15, eg = lane >> 4;
    const int ta = w * 32 + tg, tb = ta + 16;

    f32x4 accA = {0.f, 0.f, 0.f, 0.f};
    f32x4 accB = {0.f, 0.f, 0.f, 0.f};
#pragma unroll
    for (int k4 = 0; k4 < KC / 4; ++k4) {
      const f32x4 e0 = *(const f32x4*)(embL + ta * RSTRIDE + k4 * 4);
      const f32x4 e1 = *(const f32x4*)(embL + tb * RSTRIDE + k4 * 4);
#pragma unroll
      for (int h = 0; h < 4; ++h) {
        const f32x4 r = *(const f32x4*)(rwL + (k4 * 4 + h) * E_EXP + eg * 4);
        accA += e0[h] * r;
        accB += e1[h] * r;
      }
    }
    *(f32x4*)(part + ((size_t)ks * B_TOK + t0 + ta) * E_EXP + eg * 4) = accA;
    *(f32x4*)(part + ((size_t)ks * B_TOK + t0 + tb) * E_EXP + eg * 4) = accB;
  } else {
    // ---- W1 [e][h][d] fp32 -> W1T [e][d][h] bf16 ----
    typedef unsigned short TileT[65];
    TileT* tile = (TileT*)smem;                       // 64 x 65 shorts
    const int wb = blockIdx.x - 512;
    const int e  = wb >> 8;
    const int ht = (wb >> 4) & 15;
    const int dt = wb & 15;
    const float* src = w1 + ((size_t)e * H_DIM + ht * 64) * H_DIM + dt * 64;
    const int tr = tid >> 4;
    const int tc = tid & 15;
#pragma unroll
    for (int i = 0; i < 4; ++i) {
      const int r = tr + i * 16;
      const float4 v = *(const float4*)(src + (size_t)r * H_DIM + tc * 4);
      tile[r][tc * 4 + 0] = f2bf(v.x);
      tile[r][tc * 4 + 1] = f2bf(v.y);
      tile[r][tc * 4 + 2] = f2bf(v.z);
      tile[r][tc * 4 + 3] = f2bf(v.w);
    }
    __syncthreads();
    unsigned short* dst = w1t + ((size_t)e * H_DIM + dt * 64) * H_DIM + ht * 64;
    const int wr = tid >> 3;
    const int wc = tid & 7;
#pragma unroll
    for (int i = 0; i < 2; ++i) {
      const int r = wr + i * 32;
      ushort4 t0, t1;
      t0.x = tile[wc * 8 + 0][r]; t0.y = tile[wc * 8 + 1][r];
      t0.z = tile[wc * 8 + 2][r]; t0.w = tile[wc * 8 + 3][r];
      t1.x = tile[wc * 8 + 4][r]; t1.y = tile[wc * 8 + 5][r];
      t1.z = tile[wc * 8 + 6][r]; t1.w = tile[wc * 8 + 7][r];
      *(ushort4*)(dst + (size_t)r * H_DIM + wc * 8) = t0;
      *(ushort4*)(dst + (size_t)r * H_DIM + wc * 8 + 4) = t1;
    }
  }
}

// ---------------- Router select: reduce partials, top-2, compaction --------
__global__ __launch_bounds__(256) void k_router_select(
    const float* __restrict__ part, const float* __restrict__ rb,
    int* __restrict__ counts, int* __restrict__ lists,
    int4* __restrict__ meta, float2* __restrict__ wts)
{
  __shared__ int lcnt[E_EXP];
  __shared__ int base[E_EXP];
  const int tid = threadIdx.x;
  const int t = blockIdx.x * 256 + tid;
  if (tid < E_EXP) lcnt[tid] = 0;

  float lg[16];
#pragma unroll
  for (int q = 0; q < 4; ++q) {
    const f32x4 b = *(const f32x4*)(rb + q * 4);
    lg[q * 4 + 0] = b[0]; lg[q * 4 + 1] = b[1];
    lg[q * 4 + 2] = b[2]; lg[q * 4 + 3] = b[3];
  }
#pragma unroll
  for (int s = 0; s < KS; ++s) {
#pragma unroll
    for (int q = 0; q < 4; ++q) {
      const f32x4 v = *(const f32x4*)(part + ((size_t)s * B_TOK + t) * E_EXP + q * 4);
      lg[q * 4 + 0] += v[0]; lg[q * 4 + 1] += v[1];
      lg[q * 4 + 2] += v[2]; lg[q * 4 + 3] += v[3];
    }
  }

  float best = -1e30f; int b0 = 0;
#pragma unroll
  for (int e = 0; e < 16; ++e)
    if (lg[e] > best) { best = lg[e]; b0 = e; }
  float best2 = -1e30f; int b1i = 0;
#pragma unroll
  for (int e = 0; e < 16; ++e)
    if (e != b0 && lg[e] > best2) { best2 = lg[e]; b1i = e; }

  __syncthreads();                       // lcnt zeroed
  const int l0 = atomicAdd(&lcnt[b0], 1);
  const int l1 = atomicAdd(&lcnt[b1i], 1);
  __syncthreads();
  if (tid < E_EXP) base[tid] = atomicAdd(&counts[tid], lcnt[tid]);
  __syncthreads();

  const int p0 = base[b0] + l0;
  const int p1 = base[b1i] + l1;
  lists[b0 * B_TOK + p0] = t;
  lists[b1i * B_TOK + p1] = t;
  meta[t] = make_int4(b0, b1i, p0, p1);
  const float e1v = expf(best2 - best);
  const float w0 = 1.f / (1.f + e1v);
  wts[t] = make_float2(w0, e1v * w0);
}

// ---------------- Grouped GEMM, barrier-free 1-wave blocks (R14) -----------
// Session-best structure: one wave (64 threads) per block, 64x64 tile,
// 16 KB single-buffered LDS, per-wave s_waitcnt only (no __syncthreads in
// the K-loop). Every pipelining variant measured slower: block-dbuf
// (R5/R8), counted-vmcnt+s_barrier (R9/R10), 32KB per-wave dbuf (R15),
// in-block K-split (R16), BK=32 dbuf (R17), M-split (R18). Latency-bound
// at ~15% MfmaUtil; binding constraint is the per-K-step load chain over
// only ~2 waves/SIMD (work-limited: ~2048 one-wave tiles on 1024 SIMDs).
__global__ __launch_bounds__(64) void k_moe_gemm(
    const unsigned short* __restrict__ emb_bf,
    const unsigned short* __restrict__ w1t,
    const float* __restrict__ b1, const float* __restrict__ w2,
    const int* __restrict__ counts, const int* __restrict__ lists,
    float* __restrict__ outbuf)
{
  const int bid = blockIdx.x;        // 2560
  const int xcd = bid & 7;
  const int j = bid >> 3;            // 0..319
  const int e  = xcd + 8 * (j >= 160);  // experts {xcd, xcd+8} on this XCD
  const int r  = j >= 160 ? j - 160 : j;
  const int nb = r / MBS;            // 0..15 (N tile of 64)
  const int mbg = r % MBS;           // mb base, grid-stride by MBS
  const int cnt = counts[e];

  __shared__ unsigned short lA[WBM * BK];   // 8 KB, 128B rows, XOR-swizzled
  __shared__ unsigned short lB[WBN * BK];   // 8 KB, same layout

  const int lane = threadIdx.x;
  // swizzled source column byte: dest byte-in-row = (lane&7)*16, row&7 = lane>>3
  const int scb = ((lane & 7) * 16) ^ ((lane >> 3) << 4);
  const int lr = lane & 15, lg = lane >> 4;

  const unsigned short* w1tb = w1t + ((size_t)e * H_DIM + nb * WBN) * H_DIM;
  const float* b1e = b1 + (size_t)e * H_DIM + nb * WBN;
  const float* w2e = w2 + (size_t)e * H_DIM + nb * WBN;

  // B source rows (8 chunks of 1 KB), fixed across mb iterations
  const unsigned short* bSrc[8];
#pragma unroll
  for (int i = 0; i < 8; ++i) {
    const int n = i * 8 + (lane >> 3);
    bSrc[i] = w1tb + (size_t)n * H_DIM + (scb >> 1);
  }

  for (int mb = mbg; mb * WBM < cnt; mb += MBS) {
    const int base = mb * WBM;

    // A source rows: token of row i*8 + (lane>>3) for chunk i
    const unsigned short* aSrc[8];
#pragma unroll
    for (int i = 0; i < 8; ++i) {
      const int p = base + i * 8 + (lane >> 3);
      const int tok = lists[e * B_TOK + (p < cnt ? p : 0)];
      aSrc[i] = emb_bf + (size_t)tok * H_DIM + (scb >> 1);
    }

    f32x4 acc[4][4];
#pragma unroll
    for (int m = 0; m < 4; ++m)
#pragma unroll
      for (int n = 0; n < 4; ++n) acc[m][n] = (f32x4){0.f, 0.f, 0.f, 0.f};

#pragma unroll 1
    for (int k0 = 0; k0 < H_DIM; k0 += BK) {
      // WAR guard: previous step's ds_reads complete before restage
      asm volatile("s_waitcnt lgkmcnt(0)" ::: "memory");
      __builtin_amdgcn_sched_barrier(0);
#pragma unroll
      for (int i = 0; i < 8; ++i)
        gload_lds16(aSrc[i] + k0, (char*)lA + i * 1024);
#pragma unroll
      for (int i = 0; i < 8; ++i)
        gload_lds16(bSrc[i] + k0, (char*)lB + i * 1024);
      // per-wave: our 16 loads landed -> LDS visible to this wave
      asm volatile("s_waitcnt vmcnt(0)" ::: "memory");
      __builtin_amdgcn_sched_barrier(0);

#pragma unroll
      for (int kk = 0; kk < 2; ++kk) {
        const int kb = kk * 64 + lg * 16;
        bf16x8 af[4], bfr[4];
#pragma unroll
        for (int m = 0; m < 4; ++m) {
          const int row = m * 16 + lr;
          af[m] = *(const bf16x8*)((const char*)lA + row * 128 + (kb ^ ((row & 7) << 4)));
        }
#pragma unroll
        for (int n = 0; n < 4; ++n) {
          const int row = n * 16 + lr;
          bfr[n] = *(const bf16x8*)((const char*)lB + row * 128 + (kb ^ ((row & 7) << 4)));
        }
        __builtin_amdgcn_s_setprio(1);
#pragma unroll
        for (int m = 0; m < 4; ++m)
#pragma unroll
          for (int n = 0; n < 4; ++n)
            acc[m][n] = __builtin_amdgcn_mfma_f32_16x16x32_bf16(af[m], bfr[n], acc[m][n], 0, 0, 0);
        __builtin_amdgcn_s_setprio(0);
      }
    }

    // epilogue: relu(acc + b1) * w2, reduce over this wave's 64 cols
    float rs[4][4];
#pragma unroll
    for (int m = 0; m < 4; ++m)
#pragma unroll
      for (int r4 = 0; r4 < 4; ++r4) rs[m][r4] = 0.f;

#pragma unroll
    for (int n = 0; n < 4; ++n) {
      const int d = n * 16 + lr;
      const float bb = b1e[d];
      const float ww = w2e[d];
#pragma unroll
      for (int m = 0; m < 4; ++m)
#pragma unroll
        for (int r4 = 0; r4 < 4; ++r4) {
          float v = acc[m][n][r4] + bb;
          v = fmaxf(v, 0.f);
          rs[m][r4] = fmaf(v, ww, rs[m][r4]);
        }
    }
#pragma unroll
    for (int mask = 8; mask >= 1; mask >>= 1) {
#pragma unroll
      for (int m = 0; m < 4; ++m)
#pragma unroll
        for (int r4 = 0; r4 < 4; ++r4) rs[m][r4] += __shfl_xor(rs[m][r4], mask, 64);
    }

    if (lr == 0) {
      float* ob = outbuf + ((size_t)nb * E_EXP + e) * B_TOK + base;
#pragma unroll
      for (int m = 0; m < 4; ++m)
#pragma unroll
        for (int r4 = 0; r4 < 4; ++r4)
          ob[m * 16 + lg * 4 + r4] = rs[m][r4];
    }
  }
}

// ---------------- Combine: gather 2 experts x 16 partial slots -------------
__global__ __launch_bounds__(256) void k_combine(
    const int4* __restrict__ meta, const float2* __restrict__ wts,
    const float* __restrict__ outbuf, const float* __restrict__ b2,
    float* __restrict__ out)
{
  const int t = blockIdx.x * 256 + threadIdx.x;
  if (t >= B_TOK) return;
  const int4 m = meta[t];
  const float2 w = wts[t];
  float o0 = b2[m.x], o1 = b2[m.y];
#pragma unroll
  for (int s = 0; s < NSLOT; ++s) {
    o0 += outbuf[((size_t)s * E_EXP + m.x) * B_TOK + m.z];
    o1 += outbuf[((size_t)s * E_EXP + m.y) * B_TOK + m.w];
  }
  out[t] = w.x * o0 + w.y * o1;
}

extern "C" void kernel_launch(void* const* d_in, const int* in_sizes, int n_in,
                              void* d_out, int out_size, void* d_ws, size_t ws_size,
                              hipStream_t stream)
{
  const float* emb = (const float*)d_in[0];
  const float* rw  = (const float*)d_in[1];
  const float* rb  = (const float*)d_in[2];
  const float* w1  = (const float*)d_in[3];
  const float* b1  = (const float*)d_in[4];
  const float* w2  = (const float*)d_in[5];
  const float* b2  = (const float*)d_in[6];
  float* out = (float*)d_out;

  char* ws = (char*)d_ws;
  size_t cur = 0;
  auto alloc = [&](size_t bytes) -> void* {
    void* p = ws + cur;
    cur += (bytes + 255) & ~(size_t)255;
    return p;
  };
  int*            counts = (int*)alloc(64);
  int4*           meta   = (int4*)alloc((size_t)B_TOK * 16);
  float2*         wts    = (float2*)alloc((size_t)B_TOK * 8);
  int*            lists  = (int*)alloc((size_t)E_EXP * B_TOK * 4);
  float*          outbuf = (float*)alloc((size_t)NSLOT * E_EXP * B_TOK * 4);
  float*          part   = (float*)alloc((size_t)KS * B_TOK * E_EXP * 4);
  unsigned short* emb_bf = (unsigned short*)alloc((size_t)B_TOK * H_DIM * 2);
  unsigned short* w1t    = (unsigned short*)alloc((size_t)E_EXP * H_DIM * H_DIM * 2);

  k_prep<<<dim3(512 + 4096), 256, 0, stream>>>(emb, rw, w1, emb_bf, part, w1t, counts);
  k_router_select<<<B_TOK / 256, 256, 0, stream>>>(part, rb, counts, lists, meta, wts);
  k_moe_gemm<<<dim3(2 * E_EXP / 2 * 16 * MBS /*=2560*/), 64, 0, stream>>>(emb_bf, w1t, b1, w2, counts, lists, outbuf);
  k_combine<<<B_TOK / 256, 256, 0, stream>>>(meta, wts, outbuf, b2, out);
}